// Round 14
// baseline (362.134 us; speedup 1.0000x reference)
//
#include <hip/hip_runtime.h>
#include <hip/hip_bf16.h>

// ---------------------------------------------------------------------------
// RelativeTransformerEncoderLayer on MI355X (gfx950).
// B=2, S=2048, D_MODEL=1024, NHEAD=16, HEAD_DIM=64, D_FF=4096.
// R14: drop split-K on out-proj and lin2 (BM=64 grid is already 512 blocks);
//      MODE-3 f32 single output consumed by LN with P=1 -> saves ~64 MB HBM.
//      attn (swapped QK^T) / GEMM structure / LN / cvt = R13.
// ---------------------------------------------------------------------------

#define DMODEL 1024
#define NHEAD  16
#define HD     64
#define DFF    4096
#define SEQ    2048
#define BATCH  2
#define TOKD   ((size_t)4096 * 1024)   // T * DMODEL

using short8 = __attribute__((ext_vector_type(8))) short;
using f32x4  = __attribute__((ext_vector_type(4))) float;
typedef unsigned short bfu;   // raw bf16 bits

__device__ __forceinline__ bfu f2bf(float f) {
    unsigned int u = __float_as_uint(f);
    unsigned int r = (u + 0x7fffu + ((u >> 16) & 1u)) >> 16;   // RNE
    return (bfu)r;
}

__device__ __forceinline__ float gelu_exact(float x) {
    return 0.5f * x * (1.0f + erff(x * 0.70710678118654752f));
}

// async 16B global -> LDS (lds dest = wave-uniform base + lane*16)
__device__ __forceinline__ void gload16(const void* g, void* l) {
    __builtin_amdgcn_global_load_lds(
        (const __attribute__((address_space(1))) void*)g,
        (__attribute__((address_space(3))) void*)l, 16, 0, 0);
}

// swizzle for LDS tiles with 64-elem (128B) row stride (attn tiles)
__device__ __forceinline__ int swz(int row, int colbyte) {
    return (row * 128 + colbyte) ^ ((row & 7) << 4);
}

// ---------------------------------------------------------------------------
// f32 -> bf16 multi-segment convert (one launch for src + 4 weights)
// ---------------------------------------------------------------------------
struct CvtPack {
    const float* in[5];
    bfu* out[5];
    unsigned start[6];        // prefix sums, float4 units
};

__global__ __launch_bounds__(256) void cvt_multi(CvtPack p) {
    unsigned gid = blockIdx.x * 256 + threadIdx.x;
    if (gid >= p.start[5]) return;
    int i = 0;
    #pragma unroll
    for (int k = 1; k < 5; ++k) i += (gid >= p.start[k]);
    unsigned local = gid - p.start[i];
    float4 v = *(const float4*)(p.in[i] + (size_t)local * 4);
    uint2 o;
    o.x = (unsigned)f2bf(v.x) | ((unsigned)f2bf(v.y) << 16);
    o.y = (unsigned)f2bf(v.z) | ((unsigned)f2bf(v.w) << 16);
    *(uint2*)(p.out[i] + (size_t)local * 4) = o;
}

// ---------------------------------------------------------------------------
// GEMM: C[M,N] = A[M,K] * W[N,K]^T (+ bias)   (R8/R9 proven structure)
// 2-phase double-buffered (stage t+1 before compute t, one barrier/iter).
// MODE 0: +bias -> bf16   MODE 2: +bias, gelu -> bf16
// MODE 3: no bias -> f32 at Cout + z*M*N (z=0 when SPLITK==1)
// ---------------------------------------------------------------------------
template <int MODE, int BM, int SPLITK>
__global__ __launch_bounds__(256) void gemm_bt(const bfu* __restrict__ A,
                                               const bfu* __restrict__ W,
                                               const float* __restrict__ bias,
                                               void* __restrict__ Cout,
                                               int M, int N, int K) {
    constexpr int MR = BM / 32;                  // M-frags per wave
    __shared__ __align__(16) bfu As[2][BM * 32];
    __shared__ __align__(16) bfu Bs[2][128 * 32];
    const int tid = threadIdx.x;
    const int wid = tid >> 6, lane = tid & 63;
    const int lg = lane >> 4, li = lane & 15;

    // bijective XCD-aware block remap (m204)
    const int nx = gridDim.x;
    int wg = blockIdx.x + nx * blockIdx.y;
    const int nwg = nx * gridDim.y;
    {
        const int qq = nwg >> 3, rr = nwg & 7;
        const int xcd = wg & 7, idx = wg >> 3;
        wg = (xcd < rr ? xcd * (qq + 1) : rr * (qq + 1) + (xcd - rr) * qq) + idx;
    }
    const int row0 = (wg % nx) * BM, col0 = (wg / nx) * 128;
    const int wr = (wid >> 1) * (BM / 2), wc = (wid & 1) * 64;
    f32x4 acc[MR][4] = {};

    const int kchunk = K / SPLITK;
    const int kbeg = blockIdx.z * kchunk;

    const int ch_row = tid >> 2;                 // 0..63
    const int ch_col = (tid & 3) * 8;            // elem offset in row
    const bfu* Ag0 = A + (size_t)(row0 + ch_row) * K + kbeg + ch_col;
    const bfu* Ag1 = A + (size_t)(row0 + 64 + ch_row) * K + kbeg + ch_col;
    const bfu* Wg0 = W + (size_t)(col0 + ch_row) * K + kbeg + ch_col;
    const bfu* Wg1 = W + (size_t)(col0 + 64 + ch_row) * K + kbeg + ch_col;

    auto stage = [&](int buf, int k0) {
        gload16(Ag0 + k0, (char*)As[buf] + wid * 1024);
        if constexpr (BM == 128) gload16(Ag1 + k0, (char*)As[buf] + 4096 + wid * 1024);
        gload16(Wg0 + k0, (char*)Bs[buf] + wid * 1024);
        gload16(Wg1 + k0, (char*)Bs[buf] + 4096 + wid * 1024);
    };

    stage(0, 0);
    __syncthreads();                              // tile 0 resident
    int cur = 0;
    for (int k0 = 0; k0 < kchunk; k0 += 32) {
        if (k0 + 32 < kchunk) stage(cur ^ 1, k0 + 32);   // prefetch next
        short8 af[MR], bf_[4];
        #pragma unroll
        for (int m = 0; m < MR; ++m)
            af[m] = *(const short8*)(As[cur] + (wr + m * 16 + li) * 32 + lg * 8);
        #pragma unroll
        for (int n = 0; n < 4; ++n)
            bf_[n] = *(const short8*)(Bs[cur] + (wc + n * 16 + li) * 32 + lg * 8);
        #pragma unroll
        for (int m = 0; m < MR; ++m)
            #pragma unroll
            for (int n = 0; n < 4; ++n)
                acc[m][n] = __builtin_amdgcn_mfma_f32_16x16x32_bf16(af[m], bf_[n], acc[m][n], 0, 0, 0);
        __syncthreads();    // reads of cur done + prefetch drained (late)
        cur ^= 1;
    }

    float* Cp3 = (float*)Cout + (size_t)blockIdx.z * M * N;
    #pragma unroll
    for (int m = 0; m < MR; ++m) {
        #pragma unroll
        for (int n = 0; n < 4; ++n) {
            #pragma unroll
            for (int r = 0; r < 4; ++r) {
                int row = row0 + wr + m * 16 + lg * 4 + r;
                int col = col0 + wc + n * 16 + li;
                if (MODE == 3) {
                    Cp3[(size_t)row * N + col] = acc[m][n][r];
                } else {
                    float v = acc[m][n][r] + bias[col];
                    if (MODE == 2) v = gelu_exact(v);
                    ((bfu*)Cout)[(size_t)row * N + col] = f2bf(v);
                }
            }
        }
    }
}

// ---------------------------------------------------------------------------
// Flash attention, swapped QK^T (R13, best measured). Grid: (S/64, B*H),
// y -> (h=y>>1, b=y&1) for L3 bias reuse. 4 waves; KV tiles 128.
// QK^T computed as mfma(K,Q) -> s[f][r] = S[q=li][k=kt+16f+4lg+r]:
//   bias = float4/lane, softmax k-axis lane-local + 2 shfl_xor, scalar m/l.
// ---------------------------------------------------------------------------
__global__ __launch_bounds__(256) void attn_kernel(const bfu* __restrict__ qkv,
                                                   const float* __restrict__ bias,
                                                   bfu* __restrict__ ctx) {
    __shared__ __align__(16) bfu Ks[128 * 64];
    __shared__ __align__(16) bfu Vt[2][64 * 64];    // [half][d][j]
    __shared__ __align__(16) bfu Ps[4][16 * 64];    // per-wave P half-tile
    const int tid = threadIdx.x;
    const int wid = tid >> 6, lane = tid & 63;
    const int lg = lane >> 4, li = lane & 15;
    const int q0 = blockIdx.x * 64;
    const int bh = blockIdx.y;
    const int h = bh >> 1, b = bh & 1;              // b fastest -> L3 bias reuse
    const size_t tokbase = (size_t)b * SEQ;

    // ---- Q fragments in registers (B-operand; same bytes as A-frag) ----
    short8 qa[2];
    {
        const bfu* qp = qkv + (tokbase + q0 + wid * 16 + li) * 3072 + h * 64;
        qa[0] = *(const short8*)(qp + lg * 8);
        qa[1] = *(const short8*)(qp + 32 + lg * 8);
    }

    f32x4 o[4] = {};
    float m_ = -1e30f, l_ = 0.f;                    // softmax state for q = li-row

    char* pb = (char*)Ps[wid];
    const float* brow = bias + (size_t)h * SEQ * SEQ;
    const int qlane  = q0 + wid * 16 + li;          // this lane's softmax q-row
    const int qrbase = q0 + wid * 16 + lg * 4;      // O-side q rows (C layout)
    // source lane holding softmax state for O-row r: li' = 4*lg + r, same lg
    const int srcb = (lane & 48) | (((lane >> 4) & 3) << 2);

    const int krow  = tid >> 3;           // 0..31
    const int kcolb = (tid & 7) * 16;     // byte col in 128B row

    for (int kt = 0; kt < SEQ; kt += 128) {
        // ---- stage K tile 128x64 (coalesced uint4, swz writes) ----
        #pragma unroll
        for (int p = 0; p < 4; ++p) {
            int r_ = p * 32 + krow;
            uint4 v = *(const uint4*)(qkv + (tokbase + kt + r_) * 3072 + 1024 + h * 64 + (kcolb >> 1));
            *(uint4*)((char*)Ks + swz(r_, kcolb)) = v;
        }
        // ---- stage V transposed (two 64-col halves) ----
        #pragma unroll
        for (int jh = 0; jh < 2; ++jh) {
            #pragma unroll
            for (int i = 0; i < 2; ++i) {
                int jb = i * 4 + wid;     // 0..7
                bfu tmp[8];
                #pragma unroll
                for (int u = 0; u < 8; ++u)
                    tmp[u] = qkv[(tokbase + kt + jh * 64 + jb * 8 + u) * 3072 + 2048 + h * 64 + lane];
                uint4 pv;
                pv.x = (unsigned)tmp[0] | ((unsigned)tmp[1] << 16);
                pv.y = (unsigned)tmp[2] | ((unsigned)tmp[3] << 16);
                pv.z = (unsigned)tmp[4] | ((unsigned)tmp[5] << 16);
                pv.w = (unsigned)tmp[6] | ((unsigned)tmp[7] << 16);
                *(uint4*)((char*)Vt[jh] + swz(lane, jb * 16)) = pv;
            }
        }

        // ---- bias: ONE float4 per k-frag (k = kt+16f+4lg .. +3), q = qlane.
        //      Issued before the raw barrier; fly across it (no vmcnt drain).
        float4 bb[8];
        #pragma unroll
        for (int f = 0; f < 8; ++f)
            bb[f] = *(const float4*)(brow + (size_t)qlane * SEQ + kt + f * 16 + lg * 4);

        // raw barrier: LDS staging protected by lgkmcnt(0); bias loads NOT
        // drained (unlike __syncthreads' vmcnt(0))
        asm volatile("s_waitcnt lgkmcnt(0)" ::: "memory");
        __builtin_amdgcn_s_barrier();

        // ---- S^T = K Q  (16 MFMAs, swapped operands) ----
        f32x4 s[8] = {};
        __builtin_amdgcn_s_setprio(1);
        #pragma unroll
        for (int cb = 0; cb < 2; ++cb) {
            #pragma unroll
            for (int nb = 0; nb < 8; ++nb) {
                short8 kf = *(const short8*)((char*)Ks + swz(nb * 16 + li, cb * 64 + lg * 16));
                s[nb] = __builtin_amdgcn_mfma_f32_16x16x32_bf16(kf, qa[cb], s[nb], 0, 0, 0);
            }
        }
        __builtin_amdgcn_s_setprio(0);

        // ---- in-register online softmax for q = qlane ----
        float mx = -1e30f;
        #pragma unroll
        for (int f = 0; f < 8; ++f) {
            #pragma unroll
            for (int r = 0; r < 4; ++r) {
                float v = s[f][r] * 0.125f + ((const float*)&bb[f])[r];
                s[f][r] = v;
                mx = fmaxf(mx, v);
            }
        }
        mx = fmaxf(mx, __shfl_xor(mx, 16));
        mx = fmaxf(mx, __shfl_xor(mx, 32));
        float mnew = fmaxf(m_, mx);
        float sf_ = __expf(m_ - mnew);
        m_ = mnew;
        float rs = 0.f;
        #pragma unroll
        for (int f = 0; f < 8; ++f) {
            #pragma unroll
            for (int r = 0; r < 4; ++r) {
                float p = __expf(s[f][r] - mnew);
                rs += p;
                s[f][r] = p;
            }
        }
        rs += __shfl_xor(rs, 16);
        rs += __shfl_xor(rs, 32);
        l_ = l_ * sf_ + rs;

        // broadcast rescale factor to this lane's O-rows (q = 4lg+r)
        float sfq[4];
        #pragma unroll
        for (int r = 0; r < 4; ++r) sfq[r] = __shfl(sf_, srcb + r);
        #pragma unroll
        for (int dc = 0; dc < 4; ++dc)
            #pragma unroll
            for (int r = 0; r < 4; ++r) o[dc][r] *= sfq[r];

        // ---- P^T regs -> per-wave LDS (row = q = li) -> PV unchanged ----
        // P pack: truncation (P in [0,1], 0.2% downward bias - inside margin)
        #pragma unroll
        for (int jh = 0; jh < 2; ++jh) {
            #pragma unroll
            for (int nb = 0; nb < 4; ++nb)
                #pragma unroll
                for (int r = 0; r < 4; ++r)
                    *(bfu*)(pb + swz(li, (nb * 16 + lg * 4 + r) * 2)) =
                        (bfu)(__float_as_uint(s[jh * 4 + nb][r]) >> 16);
            __builtin_amdgcn_s_setprio(1);
            #pragma unroll
            for (int jb = 0; jb < 2; ++jb) {
                short8 pa = *(const short8*)(pb + swz(li, jb * 64 + lg * 16));
                short8 vb[4];
                #pragma unroll
                for (int dc = 0; dc < 4; ++dc)
                    vb[dc] = *(const short8*)((char*)Vt[jh] + swz(dc * 16 + li, jb * 64 + lg * 16));
                #pragma unroll
                for (int dc = 0; dc < 4; ++dc)
                    o[dc] = __builtin_amdgcn_mfma_f32_16x16x32_bf16(pa, vb[dc], o[dc], 0, 0, 0);
            }
            __builtin_amdgcn_s_setprio(0);
        }
        __syncthreads();
    }

    // ---- normalize (rcp of shfl'd l) + write ctx ----
    float il[4];
    #pragma unroll
    for (int r = 0; r < 4; ++r) il[r] = __builtin_amdgcn_rcpf(__shfl(l_, srcb + r));
    #pragma unroll
    for (int dc = 0; dc < 4; ++dc)
        #pragma unroll
        for (int r = 0; r < 4; ++r) {
            int qr = qrbase + r;
            int d = dc * 16 + li;
            float v = o[dc][r] * il[r];
            ctx[(tokbase + qr) * 1024 + h * 64 + d] = f2bf(v);
        }
}

// ---------------------------------------------------------------------------
// x = LayerNorm(a + sum_{i<P} parts_i + pbias) * g + be.
// ABF: 'a' is bf16 (residual read from the bf16 copy). xf/xb optional.
// ---------------------------------------------------------------------------
template <int P, bool ABF>
__global__ __launch_bounds__(256) void residual_lnP(const void* __restrict__ a,
                                                    const float* __restrict__ parts,
                                                    const float* __restrict__ pbias,
                                                    const float* __restrict__ g,
                                                    const float* __restrict__ be,
                                                    float* __restrict__ xf,
                                                    bfu* __restrict__ xb) {
    const int row = blockIdx.x, t = threadIdx.x;
    const size_t off = (size_t)row * DMODEL + t * 4;
    float4 v;
    if constexpr (ABF) {
        uint2 u = *(const uint2*)((const bfu*)a + off);
        v.x = __uint_as_float((u.x & 0xffffu) << 16);
        v.y = __uint_as_float(u.x & 0xffff0000u);
        v.z = __uint_as_float((u.y & 0xffffu) << 16);
        v.w = __uint_as_float(u.y & 0xffff0000u);
    } else {
        v = *(const float4*)((const float*)a + off);
    }
    #pragma unroll
    for (int i = 0; i < P; ++i) {
        float4 p = *(const float4*)(parts + i * TOKD + off);
        v.x += p.x; v.y += p.y; v.z += p.z; v.w += p.w;
    }
    float4 pb = *(const float4*)(pbias + t * 4);
    v.x += pb.x; v.y += pb.y; v.z += pb.z; v.w += pb.w;

    float s  = v.x + v.y + v.z + v.w;
    float sq = v.x * v.x + v.y * v.y + v.z * v.z + v.w * v.w;
    #pragma unroll
    for (int o2 = 32; o2; o2 >>= 1) { s += __shfl_xor(s, o2); sq += __shfl_xor(sq, o2); }
    __shared__ float red[8];
    const int wid = t >> 6, lane = t & 63;
    if (lane == 0) { red[wid] = s; red[4 + wid] = sq; }
    __syncthreads();
    s  = red[0] + red[1] + red[2] + red[3];
    sq = red[4] + red[5] + red[6] + red[7];
    float mu  = s * (1.0f / DMODEL);
    float var = sq * (1.0f / DMODEL) - mu * mu;
    float rstd = rsqrtf(var + 1e-5f);
    float4 gv  = *(const float4*)(g + t * 4);
    float4 bev = *(const float4*)(be + t * 4);
    float4 ov;
    ov.x = (v.x - mu) * rstd * gv.x + bev.x;
    ov.y = (v.y - mu) * rstd * gv.y + bev.y;
    ov.z = (v.z - mu) * rstd * gv.z + bev.z;
    ov.w = (v.w - mu) * rstd * gv.w + bev.w;
    if (xf) *(float4*)(xf + off) = ov;
    if (xb) {
        uint2 o;
        o.x = (unsigned)f2bf(ov.x) | ((unsigned)f2bf(ov.y) << 16);
        o.y = (unsigned)f2bf(ov.z) | ((unsigned)f2bf(ov.w) << 16);
        *(uint2*)(xb + off) = o;
    }
}

// ---------------------------------------------------------------------------
extern "C" void kernel_launch(void* const* d_in, const int* in_sizes, int n_in,
                              void* d_out, int out_size, void* d_ws, size_t ws_size,
                              hipStream_t stream) {
    const float* src    = (const float*)d_in[0];
    const float* abias  = (const float*)d_in[1];
    const float* qkv_w  = (const float*)d_in[2];
    const float* qkv_b  = (const float*)d_in[3];
    const float* out_w  = (const float*)d_in[4];
    const float* out_b  = (const float*)d_in[5];
    const float* lin1_w = (const float*)d_in[6];
    const float* lin1_b = (const float*)d_in[7];
    const float* lin2_w = (const float*)d_in[8];
    const float* lin2_b = (const float*)d_in[9];
    const float* ln1_g  = (const float*)d_in[10];
    const float* ln1_b  = (const float*)d_in[11];
    const float* ln2_g  = (const float*)d_in[12];
    const float* ln2_b  = (const float*)d_in[13];
    float* out = (float*)d_out;

    const int T = BATCH * SEQ;                    // 4096 tokens
    char* w = (char*)d_ws;
    auto take = [&](size_t bytes) { char* p = w; w += (bytes + 255) & ~(size_t)255; return p; };
    bfu*   src_bf  = (bfu*)take((size_t)T * DMODEL * 2);
    bfu*   qkvw_bf = (bfu*)take((size_t)3 * DMODEL * DMODEL * 2);
    bfu*   outw_bf = (bfu*)take((size_t)DMODEL * DMODEL * 2);
    bfu*   l1w_bf  = (bfu*)take((size_t)DFF * DMODEL * 2);
    bfu*   l2w_bf  = (bfu*)take((size_t)DMODEL * DFF * 2);
    bfu*   qkv_bf  = (bfu*)take((size_t)T * 3 * DMODEL * 2);
    bfu*   ctx_bf  = (bfu*)take((size_t)T * DMODEL * 2);
    float* attn_o  = (float*)take((size_t)T * DMODEL * 4);   // out-proj f32
    bfu*   x_bf    = (bfu*)take((size_t)T * DMODEL * 2);
    bfu*   h1_bf   = (bfu*)take((size_t)T * DFF * 2);
    float* ff_f    = (float*)take((size_t)T * DMODEL * 4);   // lin2 f32

    // one cvt launch for src + all 4 weights
    {
        CvtPack p;
        p.in[0] = src;    p.out[0] = src_bf;
        p.in[1] = qkv_w;  p.out[1] = qkvw_bf;
        p.in[2] = out_w;  p.out[2] = outw_bf;
        p.in[3] = lin1_w; p.out[3] = l1w_bf;
        p.in[4] = lin2_w; p.out[4] = l2w_bf;
        unsigned n4[5] = {
            (unsigned)((size_t)T * DMODEL / 4),
            (unsigned)((size_t)3 * DMODEL * DMODEL / 4),
            (unsigned)((size_t)DMODEL * DMODEL / 4),
            (unsigned)((size_t)DFF * DMODEL / 4),
            (unsigned)((size_t)DMODEL * DFF / 4)};
        p.start[0] = 0;
        for (int i = 0; i < 5; ++i) p.start[i + 1] = p.start[i] + n4[i];
        cvt_multi<<<(p.start[5] + 255) / 256, 256, 0, stream>>>(p);
    }

    // qkv = src @ qkv_w^T + qkv_b            [4096, 3072] bf16
    gemm_bt<0, 128, 1><<<dim3(T / 128, (3 * DMODEL) / 128, 1), 256, 0, stream>>>(
        src_bf, qkvw_bf, qkv_b, qkv_bf, T, 3 * DMODEL, DMODEL);
    // attention -> ctx                        [4096, 1024] bf16
    attn_kernel<<<dim3(SEQ / 64, BATCH * NHEAD), 256, 0, stream>>>(qkv_bf, abias, ctx_bf);
    // attn_out = ctx @ out_w^T                [4096, 1024] f32 (no split-K)
    gemm_bt<3, 64, 1><<<dim3(T / 64, DMODEL / 128, 1), 256, 0, stream>>>(
        ctx_bf, outw_bf, nullptr, attn_o, T, DMODEL, DMODEL);
    // x = LN(src + attn_o + out_b)            bf16 only
    residual_lnP<1, false><<<T, 256, 0, stream>>>(src, attn_o, out_b, ln1_g, ln1_b,
                                                  nullptr, x_bf);
    // h1 = gelu(x @ lin1_w^T + lin1_b)        [4096, 4096] bf16
    gemm_bt<2, 128, 1><<<dim3(T / 128, DFF / 128, 1), 256, 0, stream>>>(
        x_bf, l1w_bf, lin1_b, h1_bf, T, DFF, DMODEL);
    // ff = h1 @ lin2_w^T                      [4096, 1024] f32 (no split-K)
    gemm_bt<3, 64, 1><<<dim3(T / 64, DMODEL / 128, 1), 256, 0, stream>>>(
        h1_bf, l2w_bf, nullptr, ff_f, T, DMODEL, DFF);
    // out = LN(x + ff + lin2_b)               f32 -> d_out  (x read as bf16)
    residual_lnP<1, true><<<T, 256, 0, stream>>>(x_bf, ff_f, lin2_b, ln2_g, ln2_b,
                                                 out, nullptr);
}

// Round 15
// 349.030 us; speedup vs baseline: 1.0375x; 1.0375x over previous
//
#include <hip/hip_runtime.h>
#include <hip/hip_bf16.h>

// ---------------------------------------------------------------------------
// RelativeTransformerEncoderLayer on MI355X (gfx950).
// B=2, S=2048, D_MODEL=1024, NHEAD=16, HEAD_DIM=64, D_FF=4096.
// R15 = R13 (best measured, 349 us): attn swapped QK^T (mfma(K,Q) -> S^T),
//      bias float4/lane across raw barrier, lane-local softmax, trunc P-pack;
//      GEMM 2-phase dbuf + XCD swizzle; out-proj/lin2 BM=64 SK=2; fused LN.
// ---------------------------------------------------------------------------

#define DMODEL 1024
#define NHEAD  16
#define HD     64
#define DFF    4096
#define SEQ    2048
#define BATCH  2
#define TOKD   ((size_t)4096 * 1024)   // T * DMODEL

using short8 = __attribute__((ext_vector_type(8))) short;
using f32x4  = __attribute__((ext_vector_type(4))) float;
typedef unsigned short bfu;   // raw bf16 bits

__device__ __forceinline__ bfu f2bf(float f) {
    unsigned int u = __float_as_uint(f);
    unsigned int r = (u + 0x7fffu + ((u >> 16) & 1u)) >> 16;   // RNE
    return (bfu)r;
}

__device__ __forceinline__ float gelu_exact(float x) {
    return 0.5f * x * (1.0f + erff(x * 0.70710678118654752f));
}

// async 16B global -> LDS (lds dest = wave-uniform base + lane*16)
__device__ __forceinline__ void gload16(const void* g, void* l) {
    __builtin_amdgcn_global_load_lds(
        (const __attribute__((address_space(1))) void*)g,
        (__attribute__((address_space(3))) void*)l, 16, 0, 0);
}

// swizzle for LDS tiles with 64-elem (128B) row stride (attn tiles)
__device__ __forceinline__ int swz(int row, int colbyte) {
    return (row * 128 + colbyte) ^ ((row & 7) << 4);
}

// ---------------------------------------------------------------------------
// f32 -> bf16 multi-segment convert (one launch for src + 4 weights)
// ---------------------------------------------------------------------------
struct CvtPack {
    const float* in[5];
    bfu* out[5];
    unsigned start[6];        // prefix sums, float4 units
};

__global__ __launch_bounds__(256) void cvt_multi(CvtPack p) {
    unsigned gid = blockIdx.x * 256 + threadIdx.x;
    if (gid >= p.start[5]) return;
    int i = 0;
    #pragma unroll
    for (int k = 1; k < 5; ++k) i += (gid >= p.start[k]);
    unsigned local = gid - p.start[i];
    float4 v = *(const float4*)(p.in[i] + (size_t)local * 4);
    uint2 o;
    o.x = (unsigned)f2bf(v.x) | ((unsigned)f2bf(v.y) << 16);
    o.y = (unsigned)f2bf(v.z) | ((unsigned)f2bf(v.w) << 16);
    *(uint2*)(p.out[i] + (size_t)local * 4) = o;
}

// ---------------------------------------------------------------------------
// GEMM: C[M,N] = A[M,K] * W[N,K]^T (+ bias)   (R8/R9 proven structure)
// 2-phase double-buffered (stage t+1 before compute t, one barrier/iter).
// MODE 0: +bias -> bf16   MODE 2: +bias, gelu -> bf16
// MODE 3: split-K partial, no bias -> f32 at Cout + z*M*N
// ---------------------------------------------------------------------------
template <int MODE, int BM, int SPLITK>
__global__ __launch_bounds__(256) void gemm_bt(const bfu* __restrict__ A,
                                               const bfu* __restrict__ W,
                                               const float* __restrict__ bias,
                                               void* __restrict__ Cout,
                                               int M, int N, int K) {
    constexpr int MR = BM / 32;                  // M-frags per wave
    __shared__ __align__(16) bfu As[2][BM * 32];
    __shared__ __align__(16) bfu Bs[2][128 * 32];
    const int tid = threadIdx.x;
    const int wid = tid >> 6, lane = tid & 63;
    const int lg = lane >> 4, li = lane & 15;

    // bijective XCD-aware block remap (m204)
    const int nx = gridDim.x;
    int wg = blockIdx.x + nx * blockIdx.y;
    const int nwg = nx * gridDim.y;
    {
        const int qq = nwg >> 3, rr = nwg & 7;
        const int xcd = wg & 7, idx = wg >> 3;
        wg = (xcd < rr ? xcd * (qq + 1) : rr * (qq + 1) + (xcd - rr) * qq) + idx;
    }
    const int row0 = (wg % nx) * BM, col0 = (wg / nx) * 128;
    const int wr = (wid >> 1) * (BM / 2), wc = (wid & 1) * 64;
    f32x4 acc[MR][4] = {};

    const int kchunk = K / SPLITK;
    const int kbeg = blockIdx.z * kchunk;

    const int ch_row = tid >> 2;                 // 0..63
    const int ch_col = (tid & 3) * 8;            // elem offset in row
    const bfu* Ag0 = A + (size_t)(row0 + ch_row) * K + kbeg + ch_col;
    const bfu* Ag1 = A + (size_t)(row0 + 64 + ch_row) * K + kbeg + ch_col;
    const bfu* Wg0 = W + (size_t)(col0 + ch_row) * K + kbeg + ch_col;
    const bfu* Wg1 = W + (size_t)(col0 + 64 + ch_row) * K + kbeg + ch_col;

    auto stage = [&](int buf, int k0) {
        gload16(Ag0 + k0, (char*)As[buf] + wid * 1024);
        if constexpr (BM == 128) gload16(Ag1 + k0, (char*)As[buf] + 4096 + wid * 1024);
        gload16(Wg0 + k0, (char*)Bs[buf] + wid * 1024);
        gload16(Wg1 + k0, (char*)Bs[buf] + 4096 + wid * 1024);
    };

    stage(0, 0);
    __syncthreads();                              // tile 0 resident
    int cur = 0;
    for (int k0 = 0; k0 < kchunk; k0 += 32) {
        if (k0 + 32 < kchunk) stage(cur ^ 1, k0 + 32);   // prefetch next
        short8 af[MR], bf_[4];
        #pragma unroll
        for (int m = 0; m < MR; ++m)
            af[m] = *(const short8*)(As[cur] + (wr + m * 16 + li) * 32 + lg * 8);
        #pragma unroll
        for (int n = 0; n < 4; ++n)
            bf_[n] = *(const short8*)(Bs[cur] + (wc + n * 16 + li) * 32 + lg * 8);
        #pragma unroll
        for (int m = 0; m < MR; ++m)
            #pragma unroll
            for (int n = 0; n < 4; ++n)
                acc[m][n] = __builtin_amdgcn_mfma_f32_16x16x32_bf16(af[m], bf_[n], acc[m][n], 0, 0, 0);
        __syncthreads();    // reads of cur done + prefetch drained (late)
        cur ^= 1;
    }

    float* Cp3 = (float*)Cout + (size_t)blockIdx.z * M * N;
    #pragma unroll
    for (int m = 0; m < MR; ++m) {
        #pragma unroll
        for (int n = 0; n < 4; ++n) {
            #pragma unroll
            for (int r = 0; r < 4; ++r) {
                int row = row0 + wr + m * 16 + lg * 4 + r;
                int col = col0 + wc + n * 16 + li;
                if (MODE == 3) {
                    Cp3[(size_t)row * N + col] = acc[m][n][r];
                } else {
                    float v = acc[m][n][r] + bias[col];
                    if (MODE == 2) v = gelu_exact(v);
                    ((bfu*)Cout)[(size_t)row * N + col] = f2bf(v);
                }
            }
        }
    }
}

// ---------------------------------------------------------------------------
// Flash attention, swapped QK^T (best measured). Grid: (S/64, B*H),
// y -> (h=y>>1, b=y&1) for L3 bias reuse. 4 waves; KV tiles 128.
// QK^T computed as mfma(K,Q) -> s[f][r] = S[q=li][k=kt+16f+4lg+r]:
//   bias = float4/lane, softmax k-axis lane-local + 2 shfl_xor, scalar m/l.
// ---------------------------------------------------------------------------
__global__ __launch_bounds__(256) void attn_kernel(const bfu* __restrict__ qkv,
                                                   const float* __restrict__ bias,
                                                   bfu* __restrict__ ctx) {
    __shared__ __align__(16) bfu Ks[128 * 64];
    __shared__ __align__(16) bfu Vt[2][64 * 64];    // [half][d][j]
    __shared__ __align__(16) bfu Ps[4][16 * 64];    // per-wave P half-tile
    const int tid = threadIdx.x;
    const int wid = tid >> 6, lane = tid & 63;
    const int lg = lane >> 4, li = lane & 15;
    const int q0 = blockIdx.x * 64;
    const int bh = blockIdx.y;
    const int h = bh >> 1, b = bh & 1;              // b fastest -> L3 bias reuse
    const size_t tokbase = (size_t)b * SEQ;

    // ---- Q fragments in registers (B-operand; same bytes as A-frag) ----
    short8 qa[2];
    {
        const bfu* qp = qkv + (tokbase + q0 + wid * 16 + li) * 3072 + h * 64;
        qa[0] = *(const short8*)(qp + lg * 8);
        qa[1] = *(const short8*)(qp + 32 + lg * 8);
    }

    f32x4 o[4] = {};
    float m_ = -1e30f, l_ = 0.f;                    // softmax state for q = li-row

    char* pb = (char*)Ps[wid];
    const float* brow = bias + (size_t)h * SEQ * SEQ;
    const int qlane  = q0 + wid * 16 + li;          // this lane's softmax q-row
    const int qrbase = q0 + wid * 16 + lg * 4;      // O-side q rows (C layout)
    // source lane holding softmax state for O-row r: li' = 4*lg + r, same lg
    const int srcb = (lane & 48) | (((lane >> 4) & 3) << 2);

    const int krow  = tid >> 3;           // 0..31
    const int kcolb = (tid & 7) * 16;     // byte col in 128B row

    for (int kt = 0; kt < SEQ; kt += 128) {
        // ---- stage K tile 128x64 (coalesced uint4, swz writes) ----
        #pragma unroll
        for (int p = 0; p < 4; ++p) {
            int r_ = p * 32 + krow;
            uint4 v = *(const uint4*)(qkv + (tokbase + kt + r_) * 3072 + 1024 + h * 64 + (kcolb >> 1));
            *(uint4*)((char*)Ks + swz(r_, kcolb)) = v;
        }
        // ---- stage V transposed (two 64-col halves) ----
        #pragma unroll
        for (int jh = 0; jh < 2; ++jh) {
            #pragma unroll
            for (int i = 0; i < 2; ++i) {
                int jb = i * 4 + wid;     // 0..7
                bfu tmp[8];
                #pragma unroll
                for (int u = 0; u < 8; ++u)
                    tmp[u] = qkv[(tokbase + kt + jh * 64 + jb * 8 + u) * 3072 + 2048 + h * 64 + lane];
                uint4 pv;
                pv.x = (unsigned)tmp[0] | ((unsigned)tmp[1] << 16);
                pv.y = (unsigned)tmp[2] | ((unsigned)tmp[3] << 16);
                pv.z = (unsigned)tmp[4] | ((unsigned)tmp[5] << 16);
                pv.w = (unsigned)tmp[6] | ((unsigned)tmp[7] << 16);
                *(uint4*)((char*)Vt[jh] + swz(lane, jb * 16)) = pv;
            }
        }

        // ---- bias: ONE float4 per k-frag (k = kt+16f+4lg .. +3), q = qlane.
        //      Issued before the raw barrier; fly across it (no vmcnt drain).
        float4 bb[8];
        #pragma unroll
        for (int f = 0; f < 8; ++f)
            bb[f] = *(const float4*)(brow + (size_t)qlane * SEQ + kt + f * 16 + lg * 4);

        // raw barrier: LDS staging protected by lgkmcnt(0); bias loads NOT
        // drained (unlike __syncthreads' vmcnt(0))
        asm volatile("s_waitcnt lgkmcnt(0)" ::: "memory");
        __builtin_amdgcn_s_barrier();

        // ---- S^T = K Q  (16 MFMAs, swapped operands) ----
        f32x4 s[8] = {};
        __builtin_amdgcn_s_setprio(1);
        #pragma unroll
        for (int cb = 0; cb < 2; ++cb) {
            #pragma unroll
            for (int nb = 0; nb < 8; ++nb) {
                short8 kf = *(const short8*)((char*)Ks + swz(nb * 16 + li, cb * 64 + lg * 16));
                s[nb] = __builtin_amdgcn_mfma_f32_16x16x32_bf16(kf, qa[cb], s[nb], 0, 0, 0);
            }
        }
        __builtin_amdgcn_s_setprio(0);

        // ---- in-register online softmax for q = qlane ----
        float mx = -1e30f;
        #pragma unroll
        for (int f = 0; f < 8; ++f) {
            #pragma unroll
            for (int r = 0; r < 4; ++r) {
                float v = s[f][r] * 0.125f + ((const float*)&bb[f])[r];
                s[f][r] = v;
                mx = fmaxf(mx, v);
            }
        }
        mx = fmaxf(mx, __shfl_xor(mx, 16));
        mx = fmaxf(mx, __shfl_xor(mx, 32));
        float mnew = fmaxf(m_, mx);
        float sf_ = __expf(m_ - mnew);
        m_ = mnew;
        float rs = 0.f;
        #pragma unroll
        for (int f = 0; f < 8; ++f) {
            #pragma unroll
            for (int r = 0; r < 4; ++r) {
                float p = __expf(s[f][r] - mnew);
                rs += p;
                s[f][r] = p;
            }
        }
        rs += __shfl_xor(rs, 16);
        rs += __shfl_xor(rs, 32);
        l_ = l_ * sf_ + rs;

        // broadcast rescale factor to this lane's O-rows (q = 4lg+r)
        float sfq[4];
        #pragma unroll
        for (int r = 0; r < 4; ++r) sfq[r] = __shfl(sf_, srcb + r);
        #pragma unroll
        for (int dc = 0; dc < 4; ++dc)
            #pragma unroll
            for (int r = 0; r < 4; ++r) o[dc][r] *= sfq[r];

        // ---- P^T regs -> per-wave LDS (row = q = li) -> PV unchanged ----
        // P pack: truncation (P in [0,1], 0.2% downward bias - inside margin)
        #pragma unroll
        for (int jh = 0; jh < 2; ++jh) {
            #pragma unroll
            for (int nb = 0; nb < 4; ++nb)
                #pragma unroll
                for (int r = 0; r < 4; ++r)
                    *(bfu*)(pb + swz(li, (nb * 16 + lg * 4 + r) * 2)) =
                        (bfu)(__float_as_uint(s[jh * 4 + nb][r]) >> 16);
            __builtin_amdgcn_s_setprio(1);
            #pragma unroll
            for (int jb = 0; jb < 2; ++jb) {
                short8 pa = *(const short8*)(pb + swz(li, jb * 64 + lg * 16));
                short8 vb[4];
                #pragma unroll
                for (int dc = 0; dc < 4; ++dc)
                    vb[dc] = *(const short8*)((char*)Vt[jh] + swz(dc * 16 + li, jb * 64 + lg * 16));
                #pragma unroll
                for (int dc = 0; dc < 4; ++dc)
                    o[dc] = __builtin_amdgcn_mfma_f32_16x16x32_bf16(pa, vb[dc], o[dc], 0, 0, 0);
            }
            __builtin_amdgcn_s_setprio(0);
        }
        __syncthreads();
    }

    // ---- normalize (rcp of shfl'd l) + write ctx ----
    float il[4];
    #pragma unroll
    for (int r = 0; r < 4; ++r) il[r] = __builtin_amdgcn_rcpf(__shfl(l_, srcb + r));
    #pragma unroll
    for (int dc = 0; dc < 4; ++dc)
        #pragma unroll
        for (int r = 0; r < 4; ++r) {
            int qr = qrbase + r;
            int d = dc * 16 + li;
            float v = o[dc][r] * il[r];
            ctx[(tokbase + qr) * 1024 + h * 64 + d] = f2bf(v);
        }
}

// ---------------------------------------------------------------------------
// x = LayerNorm(a + sum_{i<P} parts_i + pbias) * g + be.
// ABF: 'a' is bf16 (residual read from the bf16 copy). xf/xb optional.
// ---------------------------------------------------------------------------
template <int P, bool ABF>
__global__ __launch_bounds__(256) void residual_lnP(const void* __restrict__ a,
                                                    const float* __restrict__ parts,
                                                    const float* __restrict__ pbias,
                                                    const float* __restrict__ g,
                                                    const float* __restrict__ be,
                                                    float* __restrict__ xf,
                                                    bfu* __restrict__ xb) {
    const int row = blockIdx.x, t = threadIdx.x;
    const size_t off = (size_t)row * DMODEL + t * 4;
    float4 v;
    if constexpr (ABF) {
        uint2 u = *(const uint2*)((const bfu*)a + off);
        v.x = __uint_as_float((u.x & 0xffffu) << 16);
        v.y = __uint_as_float(u.x & 0xffff0000u);
        v.z = __uint_as_float((u.y & 0xffffu) << 16);
        v.w = __uint_as_float(u.y & 0xffff0000u);
    } else {
        v = *(const float4*)((const float*)a + off);
    }
    #pragma unroll
    for (int i = 0; i < P; ++i) {
        float4 p = *(const float4*)(parts + i * TOKD + off);
        v.x += p.x; v.y += p.y; v.z += p.z; v.w += p.w;
    }
    float4 pb = *(const float4*)(pbias + t * 4);
    v.x += pb.x; v.y += pb.y; v.z += pb.z; v.w += pb.w;

    float s  = v.x + v.y + v.z + v.w;
    float sq = v.x * v.x + v.y * v.y + v.z * v.z + v.w * v.w;
    #pragma unroll
    for (int o2 = 32; o2; o2 >>= 1) { s += __shfl_xor(s, o2); sq += __shfl_xor(sq, o2); }
    __shared__ float red[8];
    const int wid = t >> 6, lane = t & 63;
    if (lane == 0) { red[wid] = s; red[4 + wid] = sq; }
    __syncthreads();
    s  = red[0] + red[1] + red[2] + red[3];
    sq = red[4] + red[5] + red[6] + red[7];
    float mu  = s * (1.0f / DMODEL);
    float var = sq * (1.0f / DMODEL) - mu * mu;
    float rstd = rsqrtf(var + 1e-5f);
    float4 gv  = *(const float4*)(g + t * 4);
    float4 bev = *(const float4*)(be + t * 4);
    float4 ov;
    ov.x = (v.x - mu) * rstd * gv.x + bev.x;
    ov.y = (v.y - mu) * rstd * gv.y + bev.y;
    ov.z = (v.z - mu) * rstd * gv.z + bev.z;
    ov.w = (v.w - mu) * rstd * gv.w + bev.w;
    if (xf) *(float4*)(xf + off) = ov;
    if (xb) {
        uint2 o;
        o.x = (unsigned)f2bf(ov.x) | ((unsigned)f2bf(ov.y) << 16);
        o.y = (unsigned)f2bf(ov.z) | ((unsigned)f2bf(ov.w) << 16);
        *(uint2*)(xb + off) = o;
    }
}

// ---------------------------------------------------------------------------
extern "C" void kernel_launch(void* const* d_in, const int* in_sizes, int n_in,
                              void* d_out, int out_size, void* d_ws, size_t ws_size,
                              hipStream_t stream) {
    const float* src    = (const float*)d_in[0];
    const float* abias  = (const float*)d_in[1];
    const float* qkv_w  = (const float*)d_in[2];
    const float* qkv_b  = (const float*)d_in[3];
    const float* out_w  = (const float*)d_in[4];
    const float* out_b  = (const float*)d_in[5];
    const float* lin1_w = (const float*)d_in[6];
    const float* lin1_b = (const float*)d_in[7];
    const float* lin2_w = (const float*)d_in[8];
    const float* lin2_b = (const float*)d_in[9];
    const float* ln1_g  = (const float*)d_in[10];
    const float* ln1_b  = (const float*)d_in[11];
    const float* ln2_g  = (const float*)d_in[12];
    const float* ln2_b  = (const float*)d_in[13];
    float* out = (float*)d_out;

    const int T = BATCH * SEQ;                    // 4096 tokens
    char* w = (char*)d_ws;
    auto take = [&](size_t bytes) { char* p = w; w += (bytes + 255) & ~(size_t)255; return p; };
    bfu*   src_bf  = (bfu*)take((size_t)T * DMODEL * 2);
    bfu*   qkvw_bf = (bfu*)take((size_t)3 * DMODEL * DMODEL * 2);
    bfu*   outw_bf = (bfu*)take((size_t)DMODEL * DMODEL * 2);
    bfu*   l1w_bf  = (bfu*)take((size_t)DFF * DMODEL * 2);
    bfu*   l2w_bf  = (bfu*)take((size_t)DMODEL * DFF * 2);
    bfu*   qkv_bf  = (bfu*)take((size_t)T * 3 * DMODEL * 2);
    bfu*   ctx_bf  = (bfu*)take((size_t)T * DMODEL * 2);
    float* outp_p  = (float*)take((size_t)2 * T * DMODEL * 4);   // split-K partials
    bfu*   x_bf    = (bfu*)take((size_t)T * DMODEL * 2);
    bfu*   h1_bf   = (bfu*)take((size_t)T * DFF * 2);
    float* l2_p    = (float*)take((size_t)2 * T * DMODEL * 4);   // split-K partials

    // one cvt launch for src + all 4 weights
    {
        CvtPack p;
        p.in[0] = src;    p.out[0] = src_bf;
        p.in[1] = qkv_w;  p.out[1] = qkvw_bf;
        p.in[2] = out_w;  p.out[2] = outw_bf;
        p.in[3] = lin1_w; p.out[3] = l1w_bf;
        p.in[4] = lin2_w; p.out[4] = l2w_bf;
        unsigned n4[5] = {
            (unsigned)((size_t)T * DMODEL / 4),
            (unsigned)((size_t)3 * DMODEL * DMODEL / 4),
            (unsigned)((size_t)DMODEL * DMODEL / 4),
            (unsigned)((size_t)DFF * DMODEL / 4),
            (unsigned)((size_t)DMODEL * DFF / 4)};
        p.start[0] = 0;
        for (int i = 0; i < 5; ++i) p.start[i + 1] = p.start[i] + n4[i];
        cvt_multi<<<(p.start[5] + 255) / 256, 256, 0, stream>>>(p);
    }

    // qkv = src @ qkv_w^T + qkv_b            [4096, 3072] bf16
    gemm_bt<0, 128, 1><<<dim3(T / 128, (3 * DMODEL) / 128, 1), 256, 0, stream>>>(
        src_bf, qkvw_bf, qkv_b, qkv_bf, T, 3 * DMODEL, DMODEL);
    // attention -> ctx                        [4096, 1024] bf16
    attn_kernel<<<dim3(SEQ / 64, BATCH * NHEAD), 256, 0, stream>>>(qkv_bf, abias, ctx_bf);
    // attn partials = ctx @ out_w^T           2 x [4096, 1024] f32 (split-K)
    gemm_bt<3, 64, 2><<<dim3(T / 64, DMODEL / 128, 2), 256, 0, stream>>>(
        ctx_bf, outw_bf, nullptr, outp_p, T, DMODEL, DMODEL);
    // x = LN(src + p0 + p1 + out_b)           bf16 only
    residual_lnP<2, false><<<T, 256, 0, stream>>>(src, outp_p, out_b, ln1_g, ln1_b,
                                                  nullptr, x_bf);
    // h1 = gelu(x @ lin1_w^T + lin1_b)        [4096, 4096] bf16
    gemm_bt<2, 128, 1><<<dim3(T / 128, DFF / 128, 1), 256, 0, stream>>>(
        x_bf, l1w_bf, lin1_b, h1_bf, T, DFF, DMODEL);
    // ff partials = h1 @ lin2_w^T             2 x [4096, 1024] f32 (split-K)
    gemm_bt<3, 64, 2><<<dim3(T / 64, DMODEL / 128, 2), 256, 0, stream>>>(
        h1_bf, l2w_bf, nullptr, l2_p, T, DMODEL, DFF);
    // out = LN(x + p0 + p1 + lin2_b)          f32 -> d_out  (x read as bf16)
    residual_lnP<2, true><<<T, 256, 0, stream>>>(x_bf, l2_p, lin2_b, ln2_g, ln2_b,
                                                 out, nullptr);
}

// Round 16
// 340.496 us; speedup vs baseline: 1.0636x; 1.0251x over previous
//
#include <hip/hip_runtime.h>
#include <hip/hip_bf16.h>

// ---------------------------------------------------------------------------
// RelativeTransformerEncoderLayer on MI355X (gfx950).
// B=2, S=2048, D_MODEL=1024, NHEAD=16, HEAD_DIM=64, D_FF=4096.
// R16 = R15 + bf16 split-K partials (MODE 3 writes bf16; LN reads bf16
//       partials): halves the 128 MB partial round-trip, occupancy unchanged.
// ---------------------------------------------------------------------------

#define DMODEL 1024
#define NHEAD  16
#define HD     64
#define DFF    4096
#define SEQ    2048
#define BATCH  2
#define TOKD   ((size_t)4096 * 1024)   // T * DMODEL (elements)

using short8 = __attribute__((ext_vector_type(8))) short;
using f32x4  = __attribute__((ext_vector_type(4))) float;
typedef unsigned short bfu;   // raw bf16 bits

__device__ __forceinline__ bfu f2bf(float f) {
    unsigned int u = __float_as_uint(f);
    unsigned int r = (u + 0x7fffu + ((u >> 16) & 1u)) >> 16;   // RNE
    return (bfu)r;
}

__device__ __forceinline__ float bf2f(bfu b) {
    return __uint_as_float((unsigned)b << 16);
}

__device__ __forceinline__ float gelu_exact(float x) {
    return 0.5f * x * (1.0f + erff(x * 0.70710678118654752f));
}

// async 16B global -> LDS (lds dest = wave-uniform base + lane*16)
__device__ __forceinline__ void gload16(const void* g, void* l) {
    __builtin_amdgcn_global_load_lds(
        (const __attribute__((address_space(1))) void*)g,
        (__attribute__((address_space(3))) void*)l, 16, 0, 0);
}

// swizzle for LDS tiles with 64-elem (128B) row stride (attn tiles)
__device__ __forceinline__ int swz(int row, int colbyte) {
    return (row * 128 + colbyte) ^ ((row & 7) << 4);
}

// ---------------------------------------------------------------------------
// f32 -> bf16 multi-segment convert (one launch for src + 4 weights)
// ---------------------------------------------------------------------------
struct CvtPack {
    const float* in[5];
    bfu* out[5];
    unsigned start[6];        // prefix sums, float4 units
};

__global__ __launch_bounds__(256) void cvt_multi(CvtPack p) {
    unsigned gid = blockIdx.x * 256 + threadIdx.x;
    if (gid >= p.start[5]) return;
    int i = 0;
    #pragma unroll
    for (int k = 1; k < 5; ++k) i += (gid >= p.start[k]);
    unsigned local = gid - p.start[i];
    float4 v = *(const float4*)(p.in[i] + (size_t)local * 4);
    uint2 o;
    o.x = (unsigned)f2bf(v.x) | ((unsigned)f2bf(v.y) << 16);
    o.y = (unsigned)f2bf(v.z) | ((unsigned)f2bf(v.w) << 16);
    *(uint2*)(p.out[i] + (size_t)local * 4) = o;
}

// ---------------------------------------------------------------------------
// GEMM: C[M,N] = A[M,K] * W[N,K]^T (+ bias)   (R8/R9 proven structure)
// 2-phase double-buffered (stage t+1 before compute t, one barrier/iter).
// MODE 0: +bias -> bf16   MODE 2: +bias, gelu -> bf16
// MODE 3: split-K partial, no bias -> bf16 at Cout + z*M*N
// ---------------------------------------------------------------------------
template <int MODE, int BM, int SPLITK>
__global__ __launch_bounds__(256) void gemm_bt(const bfu* __restrict__ A,
                                               const bfu* __restrict__ W,
                                               const float* __restrict__ bias,
                                               void* __restrict__ Cout,
                                               int M, int N, int K) {
    constexpr int MR = BM / 32;                  // M-frags per wave
    __shared__ __align__(16) bfu As[2][BM * 32];
    __shared__ __align__(16) bfu Bs[2][128 * 32];
    const int tid = threadIdx.x;
    const int wid = tid >> 6, lane = tid & 63;
    const int lg = lane >> 4, li = lane & 15;

    // bijective XCD-aware block remap (m204)
    const int nx = gridDim.x;
    int wg = blockIdx.x + nx * blockIdx.y;
    const int nwg = nx * gridDim.y;
    {
        const int qq = nwg >> 3, rr = nwg & 7;
        const int xcd = wg & 7, idx = wg >> 3;
        wg = (xcd < rr ? xcd * (qq + 1) : rr * (qq + 1) + (xcd - rr) * qq) + idx;
    }
    const int row0 = (wg % nx) * BM, col0 = (wg / nx) * 128;
    const int wr = (wid >> 1) * (BM / 2), wc = (wid & 1) * 64;
    f32x4 acc[MR][4] = {};

    const int kchunk = K / SPLITK;
    const int kbeg = blockIdx.z * kchunk;

    const int ch_row = tid >> 2;                 // 0..63
    const int ch_col = (tid & 3) * 8;            // elem offset in row
    const bfu* Ag0 = A + (size_t)(row0 + ch_row) * K + kbeg + ch_col;
    const bfu* Ag1 = A + (size_t)(row0 + 64 + ch_row) * K + kbeg + ch_col;
    const bfu* Wg0 = W + (size_t)(col0 + ch_row) * K + kbeg + ch_col;
    const bfu* Wg1 = W + (size_t)(col0 + 64 + ch_row) * K + kbeg + ch_col;

    auto stage = [&](int buf, int k0) {
        gload16(Ag0 + k0, (char*)As[buf] + wid * 1024);
        if constexpr (BM == 128) gload16(Ag1 + k0, (char*)As[buf] + 4096 + wid * 1024);
        gload16(Wg0 + k0, (char*)Bs[buf] + wid * 1024);
        gload16(Wg1 + k0, (char*)Bs[buf] + 4096 + wid * 1024);
    };

    stage(0, 0);
    __syncthreads();                              // tile 0 resident
    int cur = 0;
    for (int k0 = 0; k0 < kchunk; k0 += 32) {
        if (k0 + 32 < kchunk) stage(cur ^ 1, k0 + 32);   // prefetch next
        short8 af[MR], bf_[4];
        #pragma unroll
        for (int m = 0; m < MR; ++m)
            af[m] = *(const short8*)(As[cur] + (wr + m * 16 + li) * 32 + lg * 8);
        #pragma unroll
        for (int n = 0; n < 4; ++n)
            bf_[n] = *(const short8*)(Bs[cur] + (wc + n * 16 + li) * 32 + lg * 8);
        #pragma unroll
        for (int m = 0; m < MR; ++m)
            #pragma unroll
            for (int n = 0; n < 4; ++n)
                acc[m][n] = __builtin_amdgcn_mfma_f32_16x16x32_bf16(af[m], bf_[n], acc[m][n], 0, 0, 0);
        __syncthreads();    // reads of cur done + prefetch drained (late)
        cur ^= 1;
    }

    bfu* Cp3 = (bfu*)Cout + (size_t)blockIdx.z * M * N;
    #pragma unroll
    for (int m = 0; m < MR; ++m) {
        #pragma unroll
        for (int n = 0; n < 4; ++n) {
            #pragma unroll
            for (int r = 0; r < 4; ++r) {
                int row = row0 + wr + m * 16 + lg * 4 + r;
                int col = col0 + wc + n * 16 + li;
                if (MODE == 3) {
                    Cp3[(size_t)row * N + col] = f2bf(acc[m][n][r]);
                } else {
                    float v = acc[m][n][r] + bias[col];
                    if (MODE == 2) v = gelu_exact(v);
                    ((bfu*)Cout)[(size_t)row * N + col] = f2bf(v);
                }
            }
        }
    }
}

// ---------------------------------------------------------------------------
// Flash attention, swapped QK^T (best measured). Grid: (S/64, B*H),
// y -> (h=y>>1, b=y&1) for L3 bias reuse. 4 waves; KV tiles 128.
// QK^T computed as mfma(K,Q) -> s[f][r] = S[q=li][k=kt+16f+4lg+r]:
//   bias = float4/lane, softmax k-axis lane-local + 2 shfl_xor, scalar m/l.
// ---------------------------------------------------------------------------
__global__ __launch_bounds__(256) void attn_kernel(const bfu* __restrict__ qkv,
                                                   const float* __restrict__ bias,
                                                   bfu* __restrict__ ctx) {
    __shared__ __align__(16) bfu Ks[128 * 64];
    __shared__ __align__(16) bfu Vt[2][64 * 64];    // [half][d][j]
    __shared__ __align__(16) bfu Ps[4][16 * 64];    // per-wave P half-tile
    const int tid = threadIdx.x;
    const int wid = tid >> 6, lane = tid & 63;
    const int lg = lane >> 4, li = lane & 15;
    const int q0 = blockIdx.x * 64;
    const int bh = blockIdx.y;
    const int h = bh >> 1, b = bh & 1;              // b fastest -> L3 bias reuse
    const size_t tokbase = (size_t)b * SEQ;

    // ---- Q fragments in registers (B-operand; same bytes as A-frag) ----
    short8 qa[2];
    {
        const bfu* qp = qkv + (tokbase + q0 + wid * 16 + li) * 3072 + h * 64;
        qa[0] = *(const short8*)(qp + lg * 8);
        qa[1] = *(const short8*)(qp + 32 + lg * 8);
    }

    f32x4 o[4] = {};
    float m_ = -1e30f, l_ = 0.f;                    // softmax state for q = li-row

    char* pb = (char*)Ps[wid];
    const float* brow = bias + (size_t)h * SEQ * SEQ;
    const int qlane  = q0 + wid * 16 + li;          // this lane's softmax q-row
    const int qrbase = q0 + wid * 16 + lg * 4;      // O-side q rows (C layout)
    // source lane holding softmax state for O-row r: li' = 4*lg + r, same lg
    const int srcb = (lane & 48) | (((lane >> 4) & 3) << 2);

    const int krow  = tid >> 3;           // 0..31
    const int kcolb = (tid & 7) * 16;     // byte col in 128B row

    for (int kt = 0; kt < SEQ; kt += 128) {
        // ---- stage K tile 128x64 (coalesced uint4, swz writes) ----
        #pragma unroll
        for (int p = 0; p < 4; ++p) {
            int r_ = p * 32 + krow;
            uint4 v = *(const uint4*)(qkv + (tokbase + kt + r_) * 3072 + 1024 + h * 64 + (kcolb >> 1));
            *(uint4*)((char*)Ks + swz(r_, kcolb)) = v;
        }
        // ---- stage V transposed (two 64-col halves) ----
        #pragma unroll
        for (int jh = 0; jh < 2; ++jh) {
            #pragma unroll
            for (int i = 0; i < 2; ++i) {
                int jb = i * 4 + wid;     // 0..7
                bfu tmp[8];
                #pragma unroll
                for (int u = 0; u < 8; ++u)
                    tmp[u] = qkv[(tokbase + kt + jh * 64 + jb * 8 + u) * 3072 + 2048 + h * 64 + lane];
                uint4 pv;
                pv.x = (unsigned)tmp[0] | ((unsigned)tmp[1] << 16);
                pv.y = (unsigned)tmp[2] | ((unsigned)tmp[3] << 16);
                pv.z = (unsigned)tmp[4] | ((unsigned)tmp[5] << 16);
                pv.w = (unsigned)tmp[6] | ((unsigned)tmp[7] << 16);
                *(uint4*)((char*)Vt[jh] + swz(lane, jb * 16)) = pv;
            }
        }

        // ---- bias: ONE float4 per k-frag (k = kt+16f+4lg .. +3), q = qlane.
        //      Issued before the raw barrier; fly across it (no vmcnt drain).
        float4 bb[8];
        #pragma unroll
        for (int f = 0; f < 8; ++f)
            bb[f] = *(const float4*)(brow + (size_t)qlane * SEQ + kt + f * 16 + lg * 4);

        // raw barrier: LDS staging protected by lgkmcnt(0); bias loads NOT
        // drained (unlike __syncthreads' vmcnt(0))
        asm volatile("s_waitcnt lgkmcnt(0)" ::: "memory");
        __builtin_amdgcn_s_barrier();

        // ---- S^T = K Q  (16 MFMAs, swapped operands) ----
        f32x4 s[8] = {};
        __builtin_amdgcn_s_setprio(1);
        #pragma unroll
        for (int cb = 0; cb < 2; ++cb) {
            #pragma unroll
            for (int nb = 0; nb < 8; ++nb) {
                short8 kf = *(const short8*)((char*)Ks + swz(nb * 16 + li, cb * 64 + lg * 16));
                s[nb] = __builtin_amdgcn_mfma_f32_16x16x32_bf16(kf, qa[cb], s[nb], 0, 0, 0);
            }
        }
        __builtin_amdgcn_s_setprio(0);

        // ---- in-register online softmax for q = qlane ----
        float mx = -1e30f;
        #pragma unroll
        for (int f = 0; f < 8; ++f) {
            #pragma unroll
            for (int r = 0; r < 4; ++r) {
                float v = s[f][r] * 0.125f + ((const float*)&bb[f])[r];
                s[f][r] = v;
                mx = fmaxf(mx, v);
            }
        }
        mx = fmaxf(mx, __shfl_xor(mx, 16));
        mx = fmaxf(mx, __shfl_xor(mx, 32));
        float mnew = fmaxf(m_, mx);
        float sf_ = __expf(m_ - mnew);
        m_ = mnew;
        float rs = 0.f;
        #pragma unroll
        for (int f = 0; f < 8; ++f) {
            #pragma unroll
            for (int r = 0; r < 4; ++r) {
                float p = __expf(s[f][r] - mnew);
                rs += p;
                s[f][r] = p;
            }
        }
        rs += __shfl_xor(rs, 16);
        rs += __shfl_xor(rs, 32);
        l_ = l_ * sf_ + rs;

        // broadcast rescale factor to this lane's O-rows (q = 4lg+r)
        float sfq[4];
        #pragma unroll
        for (int r = 0; r < 4; ++r) sfq[r] = __shfl(sf_, srcb + r);
        #pragma unroll
        for (int dc = 0; dc < 4; ++dc)
            #pragma unroll
            for (int r = 0; r < 4; ++r) o[dc][r] *= sfq[r];

        // ---- P^T regs -> per-wave LDS (row = q = li) -> PV unchanged ----
        // P pack: truncation (P in [0,1], 0.2% downward bias - inside margin)
        #pragma unroll
        for (int jh = 0; jh < 2; ++jh) {
            #pragma unroll
            for (int nb = 0; nb < 4; ++nb)
                #pragma unroll
                for (int r = 0; r < 4; ++r)
                    *(bfu*)(pb + swz(li, (nb * 16 + lg * 4 + r) * 2)) =
                        (bfu)(__float_as_uint(s[jh * 4 + nb][r]) >> 16);
            __builtin_amdgcn_s_setprio(1);
            #pragma unroll
            for (int jb = 0; jb < 2; ++jb) {
                short8 pa = *(const short8*)(pb + swz(li, jb * 64 + lg * 16));
                short8 vb[4];
                #pragma unroll
                for (int dc = 0; dc < 4; ++dc)
                    vb[dc] = *(const short8*)((char*)Vt[jh] + swz(dc * 16 + li, jb * 64 + lg * 16));
                #pragma unroll
                for (int dc = 0; dc < 4; ++dc)
                    o[dc] = __builtin_amdgcn_mfma_f32_16x16x32_bf16(pa, vb[dc], o[dc], 0, 0, 0);
            }
            __builtin_amdgcn_s_setprio(0);
        }
        __syncthreads();
    }

    // ---- normalize (rcp of shfl'd l) + write ctx ----
    float il[4];
    #pragma unroll
    for (int r = 0; r < 4; ++r) il[r] = __builtin_amdgcn_rcpf(__shfl(l_, srcb + r));
    #pragma unroll
    for (int dc = 0; dc < 4; ++dc)
        #pragma unroll
        for (int r = 0; r < 4; ++r) {
            int qr = qrbase + r;
            int d = dc * 16 + li;
            float v = o[dc][r] * il[r];
            ctx[(tokbase + qr) * 1024 + h * 64 + d] = f2bf(v);
        }
}

// ---------------------------------------------------------------------------
// x = LayerNorm(a + sum_{i<P} bf16_parts_i + pbias) * g + be.
// ABF: 'a' is bf16 (residual read from the bf16 copy). xf/xb optional.
// ---------------------------------------------------------------------------
template <int P, bool ABF>
__global__ __launch_bounds__(256) void residual_lnP(const void* __restrict__ a,
                                                    const bfu* __restrict__ parts,
                                                    const float* __restrict__ pbias,
                                                    const float* __restrict__ g,
                                                    const float* __restrict__ be,
                                                    float* __restrict__ xf,
                                                    bfu* __restrict__ xb) {
    const int row = blockIdx.x, t = threadIdx.x;
    const size_t off = (size_t)row * DMODEL + t * 4;
    float4 v;
    if constexpr (ABF) {
        uint2 u = *(const uint2*)((const bfu*)a + off);
        v.x = __uint_as_float((u.x & 0xffffu) << 16);
        v.y = __uint_as_float(u.x & 0xffff0000u);
        v.z = __uint_as_float((u.y & 0xffffu) << 16);
        v.w = __uint_as_float(u.y & 0xffff0000u);
    } else {
        v = *(const float4*)((const float*)a + off);
    }
    #pragma unroll
    for (int i = 0; i < P; ++i) {
        uint2 u = *(const uint2*)(parts + i * TOKD + off);
        v.x += __uint_as_float((u.x & 0xffffu) << 16);
        v.y += __uint_as_float(u.x & 0xffff0000u);
        v.z += __uint_as_float((u.y & 0xffffu) << 16);
        v.w += __uint_as_float(u.y & 0xffff0000u);
    }
    float4 pb = *(const float4*)(pbias + t * 4);
    v.x += pb.x; v.y += pb.y; v.z += pb.z; v.w += pb.w;

    float s  = v.x + v.y + v.z + v.w;
    float sq = v.x * v.x + v.y * v.y + v.z * v.z + v.w * v.w;
    #pragma unroll
    for (int o2 = 32; o2; o2 >>= 1) { s += __shfl_xor(s, o2); sq += __shfl_xor(sq, o2); }
    __shared__ float red[8];
    const int wid = t >> 6, lane = t & 63;
    if (lane == 0) { red[wid] = s; red[4 + wid] = sq; }
    __syncthreads();
    s  = red[0] + red[1] + red[2] + red[3];
    sq = red[4] + red[5] + red[6] + red[7];
    float mu  = s * (1.0f / DMODEL);
    float var = sq * (1.0f / DMODEL) - mu * mu;
    float rstd = rsqrtf(var + 1e-5f);
    float4 gv  = *(const float4*)(g + t * 4);
    float4 bev = *(const float4*)(be + t * 4);
    float4 ov;
    ov.x = (v.x - mu) * rstd * gv.x + bev.x;
    ov.y = (v.y - mu) * rstd * gv.y + bev.y;
    ov.z = (v.z - mu) * rstd * gv.z + bev.z;
    ov.w = (v.w - mu) * rstd * gv.w + bev.w;
    if (xf) *(float4*)(xf + off) = ov;
    if (xb) {
        uint2 o;
        o.x = (unsigned)f2bf(ov.x) | ((unsigned)f2bf(ov.y) << 16);
        o.y = (unsigned)f2bf(ov.z) | ((unsigned)f2bf(ov.w) << 16);
        *(uint2*)(xb + off) = o;
    }
}

// ---------------------------------------------------------------------------
extern "C" void kernel_launch(void* const* d_in, const int* in_sizes, int n_in,
                              void* d_out, int out_size, void* d_ws, size_t ws_size,
                              hipStream_t stream) {
    const float* src    = (const float*)d_in[0];
    const float* abias  = (const float*)d_in[1];
    const float* qkv_w  = (const float*)d_in[2];
    const float* qkv_b  = (const float*)d_in[3];
    const float* out_w  = (const float*)d_in[4];
    const float* out_b  = (const float*)d_in[5];
    const float* lin1_w = (const float*)d_in[6];
    const float* lin1_b = (const float*)d_in[7];
    const float* lin2_w = (const float*)d_in[8];
    const float* lin2_b = (const float*)d_in[9];
    const float* ln1_g  = (const float*)d_in[10];
    const float* ln1_b  = (const float*)d_in[11];
    const float* ln2_g  = (const float*)d_in[12];
    const float* ln2_b  = (const float*)d_in[13];
    float* out = (float*)d_out;

    const int T = BATCH * SEQ;                    // 4096 tokens
    char* w = (char*)d_ws;
    auto take = [&](size_t bytes) { char* p = w; w += (bytes + 255) & ~(size_t)255; return p; };
    bfu*   src_bf  = (bfu*)take((size_t)T * DMODEL * 2);
    bfu*   qkvw_bf = (bfu*)take((size_t)3 * DMODEL * DMODEL * 2);
    bfu*   outw_bf = (bfu*)take((size_t)DMODEL * DMODEL * 2);
    bfu*   l1w_bf  = (bfu*)take((size_t)DFF * DMODEL * 2);
    bfu*   l2w_bf  = (bfu*)take((size_t)DMODEL * DFF * 2);
    bfu*   qkv_bf  = (bfu*)take((size_t)T * 3 * DMODEL * 2);
    bfu*   ctx_bf  = (bfu*)take((size_t)T * DMODEL * 2);
    bfu*   outp_p  = (bfu*)take((size_t)2 * T * DMODEL * 2);   // bf16 split-K partials
    bfu*   x_bf    = (bfu*)take((size_t)T * DMODEL * 2);
    bfu*   h1_bf   = (bfu*)take((size_t)T * DFF * 2);
    bfu*   l2_p    = (bfu*)take((size_t)2 * T * DMODEL * 2);   // bf16 split-K partials

    // one cvt launch for src + all 4 weights
    {
        CvtPack p;
        p.in[0] = src;    p.out[0] = src_bf;
        p.in[1] = qkv_w;  p.out[1] = qkvw_bf;
        p.in[2] = out_w;  p.out[2] = outw_bf;
        p.in[3] = lin1_w; p.out[3] = l1w_bf;
        p.in[4] = lin2_w; p.out[4] = l2w_bf;
        unsigned n4[5] = {
            (unsigned)((size_t)T * DMODEL / 4),
            (unsigned)((size_t)3 * DMODEL * DMODEL / 4),
            (unsigned)((size_t)DMODEL * DMODEL / 4),
            (unsigned)((size_t)DFF * DMODEL / 4),
            (unsigned)((size_t)DMODEL * DFF / 4)};
        p.start[0] = 0;
        for (int i = 0; i < 5; ++i) p.start[i + 1] = p.start[i] + n4[i];
        cvt_multi<<<(p.start[5] + 255) / 256, 256, 0, stream>>>(p);
    }

    // qkv = src @ qkv_w^T + qkv_b            [4096, 3072] bf16
    gemm_bt<0, 128, 1><<<dim3(T / 128, (3 * DMODEL) / 128, 1), 256, 0, stream>>>(
        src_bf, qkvw_bf, qkv_b, qkv_bf, T, 3 * DMODEL, DMODEL);
    // attention -> ctx                        [4096, 1024] bf16
    attn_kernel<<<dim3(SEQ / 64, BATCH * NHEAD), 256, 0, stream>>>(qkv_bf, abias, ctx_bf);
    // attn partials = ctx @ out_w^T           2 x [4096, 1024] bf16 (split-K)
    gemm_bt<3, 64, 2><<<dim3(T / 64, DMODEL / 128, 2), 256, 0, stream>>>(
        ctx_bf, outw_bf, nullptr, outp_p, T, DMODEL, DMODEL);
    // x = LN(src + p0 + p1 + out_b)           bf16 only
    residual_lnP<2, false><<<T, 256, 0, stream>>>(src, outp_p, out_b, ln1_g, ln1_b,
                                                  nullptr, x_bf);
    // h1 = gelu(x @ lin1_w^T + lin1_b)        [4096, 4096] bf16
    gemm_bt<2, 128, 1><<<dim3(T / 128, DFF / 128, 1), 256, 0, stream>>>(
        x_bf, l1w_bf, lin1_b, h1_bf, T, DFF, DMODEL);
    // ff partials = h1 @ lin2_w^T             2 x [4096, 1024] bf16 (split-K)
    gemm_bt<3, 64, 2><<<dim3(T / 64, DMODEL / 128, 2), 256, 0, stream>>>(
        h1_bf, l2w_bf, nullptr, l2_p, T, DMODEL, DFF);
    // out = LN(x + p0 + p1 + lin2_b)          f32 -> d_out  (x read as bf16)
    residual_lnP<2, true><<<T, 256, 0, stream>>>(x_bf, l2_p, lin2_b, ln2_g, ln2_b,
                                                 out, nullptr);
}

// Round 17
// 338.126 us; speedup vs baseline: 1.0710x; 1.0070x over previous
//
#include <hip/hip_runtime.h>
#include <hip/hip_bf16.h>

// ---------------------------------------------------------------------------
// RelativeTransformerEncoderLayer on MI355X (gfx950).
// B=2, S=2048, D_MODEL=1024, NHEAD=16, HEAD_DIM=64, D_FF=4096.
// R17 = R16 + T13 defer-max in attn (skip O-rescale when __all(mx<=m_+8);
//       P bounded by e^8, normalized out by l_). Everything else = R16.
// ---------------------------------------------------------------------------

#define DMODEL 1024
#define NHEAD  16
#define HD     64
#define DFF    4096
#define SEQ    2048
#define BATCH  2
#define TOKD   ((size_t)4096 * 1024)   // T * DMODEL (elements)

using short8 = __attribute__((ext_vector_type(8))) short;
using f32x4  = __attribute__((ext_vector_type(4))) float;
typedef unsigned short bfu;   // raw bf16 bits

__device__ __forceinline__ bfu f2bf(float f) {
    unsigned int u = __float_as_uint(f);
    unsigned int r = (u + 0x7fffu + ((u >> 16) & 1u)) >> 16;   // RNE
    return (bfu)r;
}

__device__ __forceinline__ float gelu_exact(float x) {
    return 0.5f * x * (1.0f + erff(x * 0.70710678118654752f));
}

// async 16B global -> LDS (lds dest = wave-uniform base + lane*16)
__device__ __forceinline__ void gload16(const void* g, void* l) {
    __builtin_amdgcn_global_load_lds(
        (const __attribute__((address_space(1))) void*)g,
        (__attribute__((address_space(3))) void*)l, 16, 0, 0);
}

// swizzle for LDS tiles with 64-elem (128B) row stride (attn tiles)
__device__ __forceinline__ int swz(int row, int colbyte) {
    return (row * 128 + colbyte) ^ ((row & 7) << 4);
}

// ---------------------------------------------------------------------------
// f32 -> bf16 multi-segment convert (one launch for src + 4 weights)
// ---------------------------------------------------------------------------
struct CvtPack {
    const float* in[5];
    bfu* out[5];
    unsigned start[6];        // prefix sums, float4 units
};

__global__ __launch_bounds__(256) void cvt_multi(CvtPack p) {
    unsigned gid = blockIdx.x * 256 + threadIdx.x;
    if (gid >= p.start[5]) return;
    int i = 0;
    #pragma unroll
    for (int k = 1; k < 5; ++k) i += (gid >= p.start[k]);
    unsigned local = gid - p.start[i];
    float4 v = *(const float4*)(p.in[i] + (size_t)local * 4);
    uint2 o;
    o.x = (unsigned)f2bf(v.x) | ((unsigned)f2bf(v.y) << 16);
    o.y = (unsigned)f2bf(v.z) | ((unsigned)f2bf(v.w) << 16);
    *(uint2*)(p.out[i] + (size_t)local * 4) = o;
}

// ---------------------------------------------------------------------------
// GEMM: C[M,N] = A[M,K] * W[N,K]^T (+ bias)   (R8/R9 proven structure)
// 2-phase double-buffered (stage t+1 before compute t, one barrier/iter).
// MODE 0: +bias -> bf16   MODE 2: +bias, gelu -> bf16
// MODE 3: split-K partial, no bias -> bf16 at Cout + z*M*N
// ---------------------------------------------------------------------------
template <int MODE, int BM, int SPLITK>
__global__ __launch_bounds__(256) void gemm_bt(const bfu* __restrict__ A,
                                               const bfu* __restrict__ W,
                                               const float* __restrict__ bias,
                                               void* __restrict__ Cout,
                                               int M, int N, int K) {
    constexpr int MR = BM / 32;                  // M-frags per wave
    __shared__ __align__(16) bfu As[2][BM * 32];
    __shared__ __align__(16) bfu Bs[2][128 * 32];
    const int tid = threadIdx.x;
    const int wid = tid >> 6, lane = tid & 63;
    const int lg = lane >> 4, li = lane & 15;

    // bijective XCD-aware block remap (m204)
    const int nx = gridDim.x;
    int wg = blockIdx.x + nx * blockIdx.y;
    const int nwg = nx * gridDim.y;
    {
        const int qq = nwg >> 3, rr = nwg & 7;
        const int xcd = wg & 7, idx = wg >> 3;
        wg = (xcd < rr ? xcd * (qq + 1) : rr * (qq + 1) + (xcd - rr) * qq) + idx;
    }
    const int row0 = (wg % nx) * BM, col0 = (wg / nx) * 128;
    const int wr = (wid >> 1) * (BM / 2), wc = (wid & 1) * 64;
    f32x4 acc[MR][4] = {};

    const int kchunk = K / SPLITK;
    const int kbeg = blockIdx.z * kchunk;

    const int ch_row = tid >> 2;                 // 0..63
    const int ch_col = (tid & 3) * 8;            // elem offset in row
    const bfu* Ag0 = A + (size_t)(row0 + ch_row) * K + kbeg + ch_col;
    const bfu* Ag1 = A + (size_t)(row0 + 64 + ch_row) * K + kbeg + ch_col;
    const bfu* Wg0 = W + (size_t)(col0 + ch_row) * K + kbeg + ch_col;
    const bfu* Wg1 = W + (size_t)(col0 + 64 + ch_row) * K + kbeg + ch_col;

    auto stage = [&](int buf, int k0) {
        gload16(Ag0 + k0, (char*)As[buf] + wid * 1024);
        if constexpr (BM == 128) gload16(Ag1 + k0, (char*)As[buf] + 4096 + wid * 1024);
        gload16(Wg0 + k0, (char*)Bs[buf] + wid * 1024);
        gload16(Wg1 + k0, (char*)Bs[buf] + 4096 + wid * 1024);
    };

    stage(0, 0);
    __syncthreads();                              // tile 0 resident
    int cur = 0;
    for (int k0 = 0; k0 < kchunk; k0 += 32) {
        if (k0 + 32 < kchunk) stage(cur ^ 1, k0 + 32);   // prefetch next
        short8 af[MR], bf_[4];
        #pragma unroll
        for (int m = 0; m < MR; ++m)
            af[m] = *(const short8*)(As[cur] + (wr + m * 16 + li) * 32 + lg * 8);
        #pragma unroll
        for (int n = 0; n < 4; ++n)
            bf_[n] = *(const short8*)(Bs[cur] + (wc + n * 16 + li) * 32 + lg * 8);
        #pragma unroll
        for (int m = 0; m < MR; ++m)
            #pragma unroll
            for (int n = 0; n < 4; ++n)
                acc[m][n] = __builtin_amdgcn_mfma_f32_16x16x32_bf16(af[m], bf_[n], acc[m][n], 0, 0, 0);
        __syncthreads();    // reads of cur done + prefetch drained (late)
        cur ^= 1;
    }

    bfu* Cp3 = (bfu*)Cout + (size_t)blockIdx.z * M * N;
    #pragma unroll
    for (int m = 0; m < MR; ++m) {
        #pragma unroll
        for (int n = 0; n < 4; ++n) {
            #pragma unroll
            for (int r = 0; r < 4; ++r) {
                int row = row0 + wr + m * 16 + lg * 4 + r;
                int col = col0 + wc + n * 16 + li;
                if (MODE == 3) {
                    Cp3[(size_t)row * N + col] = f2bf(acc[m][n][r]);
                } else {
                    float v = acc[m][n][r] + bias[col];
                    if (MODE == 2) v = gelu_exact(v);
                    ((bfu*)Cout)[(size_t)row * N + col] = f2bf(v);
                }
            }
        }
    }
}

// ---------------------------------------------------------------------------
// Flash attention, swapped QK^T + defer-max. Grid: (S/64, B*H),
// y -> (h=y>>1, b=y&1) for L3 bias reuse. 4 waves; KV tiles 128.
// QK^T computed as mfma(K,Q) -> s[f][r] = S[q=li][k=kt+16f+4lg+r]:
//   bias = float4/lane, softmax k-axis lane-local + 2 shfl_xor, scalar m/l.
// T13: skip the O-rescale (+shfl broadcast) when __all(mx <= m_ + 8);
//   P then bounded by e^8, absorbed by f32 accum + final l_ division.
// ---------------------------------------------------------------------------
__global__ __launch_bounds__(256) void attn_kernel(const bfu* __restrict__ qkv,
                                                   const float* __restrict__ bias,
                                                   bfu* __restrict__ ctx) {
    __shared__ __align__(16) bfu Ks[128 * 64];
    __shared__ __align__(16) bfu Vt[2][64 * 64];    // [half][d][j]
    __shared__ __align__(16) bfu Ps[4][16 * 64];    // per-wave P half-tile
    const int tid = threadIdx.x;
    const int wid = tid >> 6, lane = tid & 63;
    const int lg = lane >> 4, li = lane & 15;
    const int q0 = blockIdx.x * 64;
    const int bh = blockIdx.y;
    const int h = bh >> 1, b = bh & 1;              // b fastest -> L3 bias reuse
    const size_t tokbase = (size_t)b * SEQ;

    // ---- Q fragments in registers (B-operand; same bytes as A-frag) ----
    short8 qa[2];
    {
        const bfu* qp = qkv + (tokbase + q0 + wid * 16 + li) * 3072 + h * 64;
        qa[0] = *(const short8*)(qp + lg * 8);
        qa[1] = *(const short8*)(qp + 32 + lg * 8);
    }

    f32x4 o[4] = {};
    float m_ = -1e30f, l_ = 0.f;                    // softmax state for q = li-row

    char* pb = (char*)Ps[wid];
    const float* brow = bias + (size_t)h * SEQ * SEQ;
    const int qlane  = q0 + wid * 16 + li;          // this lane's softmax q-row
    const int qrbase = q0 + wid * 16 + lg * 4;      // O-side q rows (C layout)
    // source lane holding softmax state for O-row r: li' = 4*lg + r, same lg
    const int srcb = (lane & 48) | (((lane >> 4) & 3) << 2);

    const int krow  = tid >> 3;           // 0..31
    const int kcolb = (tid & 7) * 16;     // byte col in 128B row

    for (int kt = 0; kt < SEQ; kt += 128) {
        // ---- stage K tile 128x64 (coalesced uint4, swz writes) ----
        #pragma unroll
        for (int p = 0; p < 4; ++p) {
            int r_ = p * 32 + krow;
            uint4 v = *(const uint4*)(qkv + (tokbase + kt + r_) * 3072 + 1024 + h * 64 + (kcolb >> 1));
            *(uint4*)((char*)Ks + swz(r_, kcolb)) = v;
        }
        // ---- stage V transposed (two 64-col halves) ----
        #pragma unroll
        for (int jh = 0; jh < 2; ++jh) {
            #pragma unroll
            for (int i = 0; i < 2; ++i) {
                int jb = i * 4 + wid;     // 0..7
                bfu tmp[8];
                #pragma unroll
                for (int u = 0; u < 8; ++u)
                    tmp[u] = qkv[(tokbase + kt + jh * 64 + jb * 8 + u) * 3072 + 2048 + h * 64 + lane];
                uint4 pv;
                pv.x = (unsigned)tmp[0] | ((unsigned)tmp[1] << 16);
                pv.y = (unsigned)tmp[2] | ((unsigned)tmp[3] << 16);
                pv.z = (unsigned)tmp[4] | ((unsigned)tmp[5] << 16);
                pv.w = (unsigned)tmp[6] | ((unsigned)tmp[7] << 16);
                *(uint4*)((char*)Vt[jh] + swz(lane, jb * 16)) = pv;
            }
        }

        // ---- bias: ONE float4 per k-frag (k = kt+16f+4lg .. +3), q = qlane.
        //      Issued before the raw barrier; fly across it (no vmcnt drain).
        float4 bb[8];
        #pragma unroll
        for (int f = 0; f < 8; ++f)
            bb[f] = *(const float4*)(brow + (size_t)qlane * SEQ + kt + f * 16 + lg * 4);

        // raw barrier: LDS staging protected by lgkmcnt(0); bias loads NOT
        // drained (unlike __syncthreads' vmcnt(0))
        asm volatile("s_waitcnt lgkmcnt(0)" ::: "memory");
        __builtin_amdgcn_s_barrier();

        // ---- S^T = K Q  (16 MFMAs, swapped operands) ----
        f32x4 s[8] = {};
        __builtin_amdgcn_s_setprio(1);
        #pragma unroll
        for (int cb = 0; cb < 2; ++cb) {
            #pragma unroll
            for (int nb = 0; nb < 8; ++nb) {
                short8 kf = *(const short8*)((char*)Ks + swz(nb * 16 + li, cb * 64 + lg * 16));
                s[nb] = __builtin_amdgcn_mfma_f32_16x16x32_bf16(kf, qa[cb], s[nb], 0, 0, 0);
            }
        }
        __builtin_amdgcn_s_setprio(0);

        // ---- in-register online softmax for q = qlane (T13 defer-max) ----
        float mx = -1e30f;
        #pragma unroll
        for (int f = 0; f < 8; ++f) {
            #pragma unroll
            for (int r = 0; r < 4; ++r) {
                float v = s[f][r] * 0.125f + ((const float*)&bb[f])[r];
                s[f][r] = v;
                mx = fmaxf(mx, v);
            }
        }
        mx = fmaxf(mx, __shfl_xor(mx, 16));
        mx = fmaxf(mx, __shfl_xor(mx, 32));
        float sf_ = 1.0f;
        if (!__all(mx <= m_ + 8.0f)) {
            // rescale path: update max, rescale O via broadcast factors
            float mnew = fmaxf(m_, mx);
            sf_ = __expf(m_ - mnew);
            m_ = mnew;
            float sfq[4];
            #pragma unroll
            for (int r = 0; r < 4; ++r) sfq[r] = __shfl(sf_, srcb + r);
            #pragma unroll
            for (int dc = 0; dc < 4; ++dc)
                #pragma unroll
                for (int r = 0; r < 4; ++r) o[dc][r] *= sfq[r];
        }
        float rs = 0.f;
        #pragma unroll
        for (int f = 0; f < 8; ++f) {
            #pragma unroll
            for (int r = 0; r < 4; ++r) {
                float p = __expf(s[f][r] - m_);     // bounded by e^8 if deferred
                rs += p;
                s[f][r] = p;
            }
        }
        rs += __shfl_xor(rs, 16);
        rs += __shfl_xor(rs, 32);
        l_ = l_ * sf_ + rs;

        // ---- P^T regs -> per-wave LDS (row = q = li) -> PV unchanged ----
        // P pack: truncation (relative error ~0.4%, inside margin)
        #pragma unroll
        for (int jh = 0; jh < 2; ++jh) {
            #pragma unroll
            for (int nb = 0; nb < 4; ++nb)
                #pragma unroll
                for (int r = 0; r < 4; ++r)
                    *(bfu*)(pb + swz(li, (nb * 16 + lg * 4 + r) * 2)) =
                        (bfu)(__float_as_uint(s[jh * 4 + nb][r]) >> 16);
            __builtin_amdgcn_s_setprio(1);
            #pragma unroll
            for (int jb = 0; jb < 2; ++jb) {
                short8 pa = *(const short8*)(pb + swz(li, jb * 64 + lg * 16));
                short8 vb[4];
                #pragma unroll
                for (int dc = 0; dc < 4; ++dc)
                    vb[dc] = *(const short8*)((char*)Vt[jh] + swz(dc * 16 + li, jb * 64 + lg * 16));
                #pragma unroll
                for (int dc = 0; dc < 4; ++dc)
                    o[dc] = __builtin_amdgcn_mfma_f32_16x16x32_bf16(pa, vb[dc], o[dc], 0, 0, 0);
            }
            __builtin_amdgcn_s_setprio(0);
        }
        __syncthreads();
    }

    // ---- normalize (rcp of shfl'd l) + write ctx ----
    float il[4];
    #pragma unroll
    for (int r = 0; r < 4; ++r) il[r] = __builtin_amdgcn_rcpf(__shfl(l_, srcb + r));
    #pragma unroll
    for (int dc = 0; dc < 4; ++dc)
        #pragma unroll
        for (int r = 0; r < 4; ++r) {
            int qr = qrbase + r;
            int d = dc * 16 + li;
            float v = o[dc][r] * il[r];
            ctx[(tokbase + qr) * 1024 + h * 64 + d] = f2bf(v);
        }
}

// ---------------------------------------------------------------------------
// x = LayerNorm(a + sum_{i<P} bf16_parts_i + pbias) * g + be.
// ABF: 'a' is bf16 (residual read from the bf16 copy). xf/xb optional.
// ---------------------------------------------------------------------------
template <int P, bool ABF>
__global__ __launch_bounds__(256) void residual_lnP(const void* __restrict__ a,
                                                    const bfu* __restrict__ parts,
                                                    const float* __restrict__ pbias,
                                                    const float* __restrict__ g,
                                                    const float* __restrict__ be,
                                                    float* __restrict__ xf,
                                                    bfu* __restrict__ xb) {
    const int row = blockIdx.x, t = threadIdx.x;
    const size_t off = (size_t)row * DMODEL + t * 4;
    float4 v;
    if constexpr (ABF) {
        uint2 u = *(const uint2*)((const bfu*)a + off);
        v.x = __uint_as_float((u.x & 0xffffu) << 16);
        v.y = __uint_as_float(u.x & 0xffff0000u);
        v.z = __uint_as_float((u.y & 0xffffu) << 16);
        v.w = __uint_as_float(u.y & 0xffff0000u);
    } else {
        v = *(const float4*)((const float*)a + off);
    }
    #pragma unroll
    for (int i = 0; i < P; ++i) {
        uint2 u = *(const uint2*)(parts + i * TOKD + off);
        v.x += __uint_as_float((u.x & 0xffffu) << 16);
        v.y += __uint_as_float(u.x & 0xffff0000u);
        v.z += __uint_as_float((u.y & 0xffffu) << 16);
        v.w += __uint_as_float(u.y & 0xffff0000u);
    }
    float4 pb = *(const float4*)(pbias + t * 4);
    v.x += pb.x; v.y += pb.y; v.z += pb.z; v.w += pb.w;

    float s  = v.x + v.y + v.z + v.w;
    float sq = v.x * v.x + v.y * v.y + v.z * v.z + v.w * v.w;
    #pragma unroll
    for (int o2 = 32; o2; o2 >>= 1) { s += __shfl_xor(s, o2); sq += __shfl_xor(sq, o2); }
    __shared__ float red[8];
    const int wid = t >> 6, lane = t & 63;
    if (lane == 0) { red[wid] = s; red[4 + wid] = sq; }
    __syncthreads();
    s  = red[0] + red[1] + red[2] + red[3];
    sq = red[4] + red[5] + red[6] + red[7];
    float mu  = s * (1.0f / DMODEL);
    float var = sq * (1.0f / DMODEL) - mu * mu;
    float rstd = rsqrtf(var + 1e-5f);
    float4 gv  = *(const float4*)(g + t * 4);
    float4 bev = *(const float4*)(be + t * 4);
    float4 ov;
    ov.x = (v.x - mu) * rstd * gv.x + bev.x;
    ov.y = (v.y - mu) * rstd * gv.y + bev.y;
    ov.z = (v.z - mu) * rstd * gv.z + bev.z;
    ov.w = (v.w - mu) * rstd * gv.w + bev.w;
    if (xf) *(float4*)(xf + off) = ov;
    if (xb) {
        uint2 o;
        o.x = (unsigned)f2bf(ov.x) | ((unsigned)f2bf(ov.y) << 16);
        o.y = (unsigned)f2bf(ov.z) | ((unsigned)f2bf(ov.w) << 16);
        *(uint2*)(xb + off) = o;
    }
}

// ---------------------------------------------------------------------------
extern "C" void kernel_launch(void* const* d_in, const int* in_sizes, int n_in,
                              void* d_out, int out_size, void* d_ws, size_t ws_size,
                              hipStream_t stream) {
    const float* src    = (const float*)d_in[0];
    const float* abias  = (const float*)d_in[1];
    const float* qkv_w  = (const float*)d_in[2];
    const float* qkv_b  = (const float*)d_in[3];
    const float* out_w  = (const float*)d_in[4];
    const float* out_b  = (const float*)d_in[5];
    const float* lin1_w = (const float*)d_in[6];
    const float* lin1_b = (const float*)d_in[7];
    const float* lin2_w = (const float*)d_in[8];
    const float* lin2_b = (const float*)d_in[9];
    const float* ln1_g  = (const float*)d_in[10];
    const float* ln1_b  = (const float*)d_in[11];
    const float* ln2_g  = (const float*)d_in[12];
    const float* ln2_b  = (const float*)d_in[13];
    float* out = (float*)d_out;

    const int T = BATCH * SEQ;                    // 4096 tokens
    char* w = (char*)d_ws;
    auto take = [&](size_t bytes) { char* p = w; w += (bytes + 255) & ~(size_t)255; return p; };
    bfu*   src_bf  = (bfu*)take((size_t)T * DMODEL * 2);
    bfu*   qkvw_bf = (bfu*)take((size_t)3 * DMODEL * DMODEL * 2);
    bfu*   outw_bf = (bfu*)take((size_t)DMODEL * DMODEL * 2);
    bfu*   l1w_bf  = (bfu*)take((size_t)DFF * DMODEL * 2);
    bfu*   l2w_bf  = (bfu*)take((size_t)DMODEL * DFF * 2);
    bfu*   qkv_bf  = (bfu*)take((size_t)T * 3 * DMODEL * 2);
    bfu*   ctx_bf  = (bfu*)take((size_t)T * DMODEL * 2);
    bfu*   outp_p  = (bfu*)take((size_t)2 * T * DMODEL * 2);   // bf16 split-K partials
    bfu*   x_bf    = (bfu*)take((size_t)T * DMODEL * 2);
    bfu*   h1_bf   = (bfu*)take((size_t)T * DFF * 2);
    bfu*   l2_p    = (bfu*)take((size_t)2 * T * DMODEL * 2);   // bf16 split-K partials

    // one cvt launch for src + all 4 weights
    {
        CvtPack p;
        p.in[0] = src;    p.out[0] = src_bf;
        p.in[1] = qkv_w;  p.out[1] = qkvw_bf;
        p.in[2] = out_w;  p.out[2] = outw_bf;
        p.in[3] = lin1_w; p.out[3] = l1w_bf;
        p.in[4] = lin2_w; p.out[4] = l2w_bf;
        unsigned n4[5] = {
            (unsigned)((size_t)T * DMODEL / 4),
            (unsigned)((size_t)3 * DMODEL * DMODEL / 4),
            (unsigned)((size_t)DMODEL * DMODEL / 4),
            (unsigned)((size_t)DFF * DMODEL / 4),
            (unsigned)((size_t)DMODEL * DFF / 4)};
        p.start[0] = 0;
        for (int i = 0; i < 5; ++i) p.start[i + 1] = p.start[i] + n4[i];
        cvt_multi<<<(p.start[5] + 255) / 256, 256, 0, stream>>>(p);
    }

    // qkv = src @ qkv_w^T + qkv_b            [4096, 3072] bf16
    gemm_bt<0, 128, 1><<<dim3(T / 128, (3 * DMODEL) / 128, 1), 256, 0, stream>>>(
        src_bf, qkvw_bf, qkv_b, qkv_bf, T, 3 * DMODEL, DMODEL);
    // attention -> ctx                        [4096, 1024] bf16
    attn_kernel<<<dim3(SEQ / 64, BATCH * NHEAD), 256, 0, stream>>>(qkv_bf, abias, ctx_bf);
    // attn partials = ctx @ out_w^T           2 x [4096, 1024] bf16 (split-K)
    gemm_bt<3, 64, 2><<<dim3(T / 64, DMODEL / 128, 2), 256, 0, stream>>>(
        ctx_bf, outw_bf, nullptr, outp_p, T, DMODEL, DMODEL);
    // x = LN(src + p0 + p1 + out_b)           bf16 only
    residual_lnP<2, false><<<T, 256, 0, stream>>>(src, outp_p, out_b, ln1_g, ln1_b,
                                                  nullptr, x_bf);
    // h1 = gelu(x @ lin1_w^T + lin1_b)        [4096, 4096] bf16
    gemm_bt<2, 128, 1><<<dim3(T / 128, DFF / 128, 1), 256, 0, stream>>>(
        x_bf, l1w_bf, lin1_b, h1_bf, T, DFF, DMODEL);
    // ff partials = h1 @ lin2_w^T             2 x [4096, 1024] bf16 (split-K)
    gemm_bt<3, 64, 2><<<dim3(T / 64, DMODEL / 128, 2), 256, 0, stream>>>(
        h1_bf, l2w_bf, nullptr, l2_p, T, DMODEL, DFF);
    // out = LN(x + p0 + p1 + lin2_b)          f32 -> d_out  (x read as bf16)
    residual_lnP<2, true><<<T, 256, 0, stream>>>(x_bf, l2_p, lin2_b, ln2_g, ln2_b,
                                                 out, nullptr);
}